// Round 7
// baseline (45.058 us; speedup 1.0000x reference)
//
#include <hip/hip_runtime.h>

// Problem constants (fixed by setup_inputs in the reference)
constexpr int N_  = 8;
constexpr int B_  = 64;
constexpr int C_  = 32;
constexpr int H_  = 256;
constexpr int W_  = 256;
constexpr int PH_ = 8;
constexpr int HW_ = H_ * W_;
constexpr int NB_ = N_ * B_;
constexpr int CPT_ = 8;           // channels per thread
constexpr int CB_  = C_ / CPT_;   // 4 channel-blocks

// 8-byte load at 4-byte alignment.
struct __attribute__((packed, aligned(4))) f2u { float a, b; };

// One block = (nb, cb, pm-chunk), XCD-clustered (all blocks of one box land on
// one XCD for L2 locality — proven r6: FETCH 117->60 MB).
// One thread = one sample point x 8 channels; sample computed once, stored to
// both directions. r7: sched_barrier(0) pins all 16 gathers before first use
// so each wave keeps ~16 loads outstanding (r6 compiler re-serialized to ~3).
__global__ __launch_bounds__(256)
void boxpool_v7(const float* __restrict__ x, const float* __restrict__ boxes,
                float* __restrict__ out, int MW, int PM, unsigned M16,
                int G, int pmb, long featsSize)
{
    const int Bx  = blockIdx.x;
    const int xcd = Bx & 7;
    const int s   = Bx >> 3;
    const int bq  = s / G;                 // box index within this XCD's share
    const int g   = s - bq * G;
    const int nb  = xcd * (NB_ / 8) + bq;  // 64 boxes per XCD
    const int cb  = g / pmb;
    const int pmblk = g - cb * pmb;
    const int tid = threadIdx.x;
    const int pm  = pmblk * 256 + tid;

    // ---- box parameters (nb uniform per block -> scalar loads)
    const float* bp = boxes + (long)nb * 4;
    const float xmin = bp[0], ymin = bp[1], xmax = bp[2], ymax = bp[3];
    const bool is_zero = (xmin == 0.f) && (ymin == 0.f) && (xmax == 0.f) && (ymax == 0.f);
    const float bw = xmax - xmin, bh = ymax - ymin;
    const bool wide = bw > bh;
    float den = wide ? bh : bw;
    den = (den == 0.f) ? 1.f : den;
    const float ratio = (wide ? bw : bh) / den;
    const float wf = ceilf(ratio * (float)PH_);
    const float wm1 = (wf > 1.f) ? (wf - 1.f) : 1.f;

    // widths tail (N,B,2): one writer per box
    if (g == 0 && tid == 0) {
        float wv = is_zero ? 0.f : wf;
        out[featsSize + (long)nb * 2 + 0] = wv;
        out[featsSize + (long)nb * 2 + 1] = wv;
    }

    if (pm >= PM) return;

    const int i = (int)(((unsigned)pm * M16) >> 16);   // pm / MW via magic
    const int j = pm - i * MW;
    const int n = nb >> 6;                             // B_ = 64
    const int c0 = cb * CPT_;

    const long obase = (long)nb * (2 * C_ * PM);
    float* o0p = out + obase + (long)c0 * PM + pm;                    // d=0 @ (i,j)

    const bool valid = !is_zero && ((float)j < wf);
    if (!valid) {
        float* o1p = out + obase + (long)(C_ + c0) * PM + pm;         // d=1 @ (i,j)
        #pragma unroll
        for (int k = 0; k < CPT_; ++k) {
            o0p[(long)k * PM] = 0.f;
            o1p[(long)k * PM] = 0.f;
        }
        return;
    }

    const int i2 = (PH_ - 1) - i;
    const int j2 = (int)wf - 1 - j;
    float* o1p = out + obase + (long)(C_ + c0) * PM + (long)i2 * MW + j2;  // d=1 @ flipped

    // ---- sample coordinates (pixels), forward grid at (i,j)
    const float fi = (float)i, fj = (float)j;
    float xs, ys;
    if (wide) {
        xs = xmin + fj * (bw / wm1);
        ys = ymin + fi * (bh * (1.f / (float)(PH_ - 1)));
    } else {
        xs = xmin + fi * (bw * (1.f / (float)(PH_ - 1)));
        ys = ymin + (wf - fj) * (bh / wm1);
    }
    const float ix = xs - 0.5f;   // ((gx+1)*W - 1)/2 == xs - 0.5 exactly
    const float iy = ys - 0.5f;
    const float x0f = floorf(ix), y0f = floorf(iy);
    const int   x0  = (int)x0f,  y0  = (int)y0f;

    float wx1 = ix - x0f, wx0 = 1.f - wx1;
    float wy1 = iy - y0f, wy0 = 1.f - wy1;

    if (y0 < 0 || y0 >= H_)         wy0 = 0.f;
    if (y0 + 1 < 0 || y0 + 1 >= H_) wy1 = 0.f;
    const int y0c = min(max(y0, 0), H_ - 1);
    const int y1c = min(max(y0 + 1, 0), H_ - 1);

    if (x0 < 0 || x0 >= W_)         wx0 = 0.f;
    if (x0 + 1 < 0 || x0 + 1 >= W_) wx1 = 0.f;
    const int bx = min(max(x0, 0), W_ - 2);
    const float wl = (bx == x0) ? wx0 : ((bx == x0 + 1) ? wx1 : 0.f);
    const float wr = (bx + 1 == x0 + 1) ? wx1 : ((bx + 1 == x0) ? wx0 : 0.f);

    const int o0 = y0c * W_ + bx;
    const int o1 = y1c * W_ + bx;
    const float w00 = wl * wy0, w01 = wr * wy0;
    const float w10 = wl * wy1, w11 = wr * wy1;

    // ---- phase 1: issue all 16 gathers; fence pins them before any use so
    // they stay in flight together (defeats register-minimizing reordering).
    const float* xp = x + (long)(n * C_ + c0) * HW_;
    f2u r0[CPT_], r1[CPT_];
    #pragma unroll
    for (int k = 0; k < CPT_; ++k) {
        r0[k] = *reinterpret_cast<const f2u*>(xp + (long)k * HW_ + o0);
        r1[k] = *reinterpret_cast<const f2u*>(xp + (long)k * HW_ + o1);
    }
    __builtin_amdgcn_sched_barrier(0);

    // ---- phase 2: compute + store both directions (compiler emits
    // progressive vmcnt(N) waits per k -> pipelined drain).
    #pragma unroll
    for (int k = 0; k < CPT_; ++k) {
        float v = w00 * r0[k].a + w01 * r0[k].b + w10 * r1[k].a + w11 * r1[k].b;
        o0p[(long)k * PM] = v;
        o1p[(long)k * PM] = v;
    }
}

extern "C" void kernel_launch(void* const* d_in, const int* in_sizes, int n_in,
                              void* d_out, int out_size, void* d_ws, size_t ws_size,
                              hipStream_t stream)
{
    const float* x     = (const float*)d_in[0];
    const float* boxes = (const float*)d_in[1];
    float* out = (float*)d_out;

    long total      = (long)out_size;
    long widthsSize = (long)N_ * B_ * 2;
    long featsSize  = total - widthsSize;
    int  MW         = (int)(featsSize / ((long)N_ * B_ * 2 * C_ * PH_));
    int  PM         = PH_ * MW;

    int pmb = (PM + 255) / 256;       // pm-chunks per (nb, cb)
    int G   = CB_ * pmb;              // blocks per box
    int blocks = NB_ * G;             // divisible by 8 (NB_=512)

    unsigned M16 = (65536u + (unsigned)MW - 1u) / (unsigned)MW;   // pm/MW magic

    hipLaunchKernelGGL(boxpool_v7, dim3(blocks), dim3(256), 0, stream,
                       x, boxes, out, MW, PM, M16, G, pmb, featsSize);
}